// Round 10
// baseline (39.805 us; speedup 1.0000x reference)
//
#include <hip/hip_runtime.h>
#include <hip/hip_fp16.h>

#define G_ 8
#define C_ 64
#define K_ 9
#define H_ 100
#define W_ 160
#define TW_ 16
#define TH_ 8
#define HALO_ 4
#define SW_ (TW_ + 2*HALO_)       // 24 staged cols
#define SH_ (TH_ + 2*HALO_)       // 16 staged rows
#define NREC_ (SW_ * SH_)         // 384 records
#define RECU_ 9                   // 72 B record stride, in u64 units (odd -> bank sweep)
#define LDSU_ (NREC_ * RECU_)     // 3456 u64 = 27648 B -> 4 blocks/CU (wave-slot capped)

// One block = (group g, channel-half c, 16x8 pixel tile), 512 threads = 8 waves.
// Stages its 32-channel slice of tile+halo (f32->f16, 64 B/record, XOR-chunk
// swizzle, 72 B stride). 4 threads/pixel, 8 channels each -> per-corner fetch
// = one ds_read_b128. Softmax hoisted before the staging barrier. Rare
// out-of-halo corners take a predicated exact global-f32 fallback.
__global__ __launch_bounds__(512, 8) void dcn_lds_kernel(
    const float* __restrict__ x,      // [H,W,G*C] f32
    const float* __restrict__ offset, // [H,W,G*K*2]
    const float* __restrict__ mask,   // [H,W,G*K]
    float* __restrict__ out)          // [H,W,G*C]
{
    __shared__ unsigned long long sm[LDSU_];
    const int bid = (int)blockIdx.x;
    const int c   = bid & 1;          // channel half
    const int g   = (bid >> 1) & 7;   // group
    const int t   = bid >> 4;         // 0..129 tile id
    const int th  = t / 10, twc = t % 10;
    const int h0  = th * TH_, w0 = twc * TW_;
    const int tid = (int)threadIdx.x;

    // ---- per-thread pixel/channel mapping (compute phase) ----
    const int p   = tid >> 2;           // 0..127 pixel in tile
    const int q   = tid & 3;            // 16-B chunk within the 64-B record
    const int chb = c * 32 + q * 8;     // channel base (8 channels)
    const int hh  = h0 + (p >> 4);
    const int ww  = w0 + (p & 15);
    const bool live = (hh < H_);        // ragged bottom tile
    const int pixg = (hh * W_ + ww) * G_ + g;

    // ---- softmax hoisted BEFORE barrier (overlaps staging latency) ----
    float mv[K_];
    float minv = 0.f;
    if (live) {
        const float* mptr = mask + (size_t)pixg * K_;
        float mmax = -1e30f;
#pragma unroll
        for (int k = 0; k < K_; ++k) { mv[k] = mptr[k]; mmax = fmaxf(mmax, mv[k]); }
        float msum = 0.f;
#pragma unroll
        for (int k = 0; k < K_; ++k) { mv[k] = __expf(mv[k] - mmax); msum += mv[k]; }
        minv = 1.f / msum;
    }

    // ---------------- stage x slice (f32 -> f16, swizzled) ----------------
    // tasks: 384 records x 4 chunks (16 B f16 <- 32 B f32) = 1536 = 3 x 512
#pragma unroll
    for (int it = 0; it < 3; ++it) {
        const int task = it * 512 + tid;
        const int rec = task >> 2, sub = task & 3;
        const int i = rec / SW_, j = rec - i * SW_;
        const int hs = h0 - HALO_ + i, ws = w0 - HALO_ + j;
        if (hs >= 0 && hs < H_ && ws >= 0 && ws < W_) {
            const float* src = x + (size_t)(hs * W_ + ws) * (G_ * C_)
                                 + g * C_ + c * 32 + sub * 8;
            const float4 A = *(const float4*)src;
            const float4 B = *(const float4*)(src + 4);
            __half2 p0 = __floats2half2_rn(A.x, A.y);
            __half2 p1 = __floats2half2_rn(A.z, A.w);
            __half2 p2 = __floats2half2_rn(B.x, B.y);
            __half2 p3 = __floats2half2_rn(B.z, B.w);
            const unsigned long long lo =
                ((unsigned long long)*(unsigned*)&p1 << 32) | *(unsigned*)&p0;
            const unsigned long long hi =
                ((unsigned long long)*(unsigned*)&p3 << 32) | *(unsigned*)&p2;
            const int base = rec * RECU_ + ((sub ^ (rec & 3)) << 1);
            sm[base]     = lo;
            sm[base + 1] = hi;
        }
    }
    __syncthreads();

    if (!live) return;

    const float* optr = offset + (size_t)pixg * (K_ * 2);

    // 3 f16 accumulation groups (k 0-2 / 3-5 / 6-8), 4 half2 = 8 ch each
    __half2 acc[3][4];
#pragma unroll
    for (int gr = 0; gr < 3; ++gr)
#pragma unroll
        for (int u = 0; u < 4; ++u) acc[gr][u] = __half2(__half(0.f), __half(0.f));

#pragma unroll
    for (int k = 0; k < K_; ++k) {
        const int gr = k / 3;
        const float lh = (float)(hh + k / 3 - 1) + optr[2 * k];
        const float lw = (float)(ww + k % 3 - 1) + optr[2 * k + 1];
        const float fh0 = floorf(lh), fw0 = floorf(lw);
        const float ft = lh - fh0, gt = lw - fw0;
        const int hI = (int)fh0, wI = (int)fw0;
        const float m = mv[k] * minv;

        const float wh0 = (hI >= 0  && hI < H_    ) ? (1.f - ft) * m : 0.f;
        const float wh1 = (hI >= -1 && hI < H_ - 1) ? ft * m         : 0.f;
        const float cw0 = (wI >= 0  && wI < W_    ) ? (1.f - gt)     : 0.f;
        const float cw1 = (wI >= -1 && wI < W_ - 1) ? gt             : 0.f;
        const __half2 W00 = __float2half2_rn(wh0 * cw0);
        const __half2 W01 = __float2half2_rn(wh0 * cw1);
        const __half2 W10 = __float2half2_rn(wh1 * cw0);
        const __half2 W11 = __float2half2_rn(wh1 * cw1);

        const int hc0 = min(max(hI,     0), H_ - 1);
        const int hc1 = min(max(hI + 1, 0), H_ - 1);
        const int wc0 = min(max(wI,     0), W_ - 1);
        const int wc1 = min(max(wI + 1, 0), W_ - 1);

        // both corners (pre-clamp) inside staged halo box?
        const bool inbox = (hI >= h0 - HALO_) && (hI <= h0 + TH_ + HALO_ - 2) &&
                           (wI >= w0 - HALO_) && (wI <= w0 + TW_ + HALO_ - 2);

        if (inbox) {
            const int ri0 = hc0 - (h0 - HALO_), ri1 = hc1 - (h0 - HALO_);
            const int rj0 = wc0 - (w0 - HALO_), rj1 = wc1 - (w0 - HALO_);
            const int r00 = ri0 * SW_ + rj0, r01 = ri0 * SW_ + rj1;
            const int r10 = ri1 * SW_ + rj0, r11 = ri1 * SW_ + rj1;

#define CORNER(REC, WT)                                                       \
            {                                                                 \
                const int b = (REC) * RECU_ + ((q ^ ((REC) & 3)) << 1);       \
                const unsigned long long qa = sm[b], qb = sm[b + 1];          \
                unsigned u32;                                                 \
                u32 = (unsigned)qa;         acc[gr][0] = __hfma2(*(__half2*)&u32, (WT), acc[gr][0]); \
                u32 = (unsigned)(qa >> 32); acc[gr][1] = __hfma2(*(__half2*)&u32, (WT), acc[gr][1]); \
                u32 = (unsigned)qb;         acc[gr][2] = __hfma2(*(__half2*)&u32, (WT), acc[gr][2]); \
                u32 = (unsigned)(qb >> 32); acc[gr][3] = __hfma2(*(__half2*)&u32, (WT), acc[gr][3]); \
            }
            CORNER(r00, W00) CORNER(r01, W01) CORNER(r10, W10) CORNER(r11, W11)
#undef CORNER
        } else {
            // rare: direct global f32 loads at clamped coords (exact)
#define GCORNER(HC, WC, WT)                                                   \
            {                                                                 \
                const float* s = x + (size_t)((HC) * W_ + (WC)) * (G_ * C_) + g * C_ + chb; \
                const float4 v0 = *(const float4*)s;                          \
                const float4 v1 = *(const float4*)(s + 4);                    \
                __half2 e0 = __floats2half2_rn(v0.x, v0.y);                   \
                __half2 e1 = __floats2half2_rn(v0.z, v0.w);                   \
                __half2 e2 = __floats2half2_rn(v1.x, v1.y);                   \
                __half2 e3 = __floats2half2_rn(v1.z, v1.w);                   \
                acc[gr][0] = __hfma2(e0, (WT), acc[gr][0]);                   \
                acc[gr][1] = __hfma2(e1, (WT), acc[gr][1]);                   \
                acc[gr][2] = __hfma2(e2, (WT), acc[gr][2]);                   \
                acc[gr][3] = __hfma2(e3, (WT), acc[gr][3]);                   \
            }
            GCORNER(hc0, wc0, W00) GCORNER(hc0, wc1, W01)
            GCORNER(hc1, wc0, W10) GCORNER(hc1, wc1, W11)
#undef GCORNER
        }
    }

    // fold 3 f16 groups in f32, store 8 channels (2x float4, coalesced)
    float* op = out + (size_t)pixg * C_ + chb;
#pragma unroll
    for (int a = 0; a < 4; a += 2) {
        const float2 s0 = __half22float2(acc[0][a]);
        const float2 t1 = __half22float2(acc[1][a]);
        const float2 t2 = __half22float2(acc[2][a]);
        const float2 s1 = __half22float2(acc[0][a + 1]);
        const float2 t3 = __half22float2(acc[1][a + 1]);
        const float2 t4 = __half22float2(acc[2][a + 1]);
        float4 o;
        o.x = s0.x + t1.x + t2.x;
        o.y = s0.y + t1.y + t2.y;
        o.z = s1.x + t3.x + t4.x;
        o.w = s1.y + t3.y + t4.y;
        *(float4*)(op + a * 2) = o;
    }
}

extern "C" void kernel_launch(void* const* d_in, const int* in_sizes, int n_in,
                              void* d_out, int out_size, void* d_ws, size_t ws_size,
                              hipStream_t stream) {
    const float* x      = (const float*)d_in[0];
    const float* offset = (const float*)d_in[1];
    const float* mask   = (const float*)d_in[2];
    float* out          = (float*)d_out;

    // 13x10 tiles x 8 groups x 2 channel-halves = 2080 blocks
    dcn_lds_kernel<<<2080, 512, 0, stream>>>(x, offset, mask, out);
}